// Round 11
// baseline (17.668 us; speedup 1.0000x reference)
//
#include <hip/hip_runtime.h>

#define R 128
#define C 256
#define P 7
#define HW 64
#define SW 72   // slab row stride: max touched index sx+7 <= 69 < 72

__global__ __launch_bounds__(256) void
roi_pool_kernel(const float* __restrict__ x,
                const int* __restrict__ rois,
                float* __restrict__ out) {
    const int lane = threadIdx.x & 63;
    const int wid  = __builtin_amdgcn_readfirstlane(threadIdx.x >> 6);
    const int gw   = blockIdx.x * 4 + wid;   // wave id = r*128 + cpair
    const int cp = gw & 127;                 // channels c = 2cp, 2cp+1
    const int r  = gw >> 7;

    __shared__ float vmbuf[4][2 * P * SW];   // [wave][ch][py][SW] = 16.1 KB
    float* slab = vmbuf[wid];

    const int rx = rois[r * 4 + 0];          // r uniform -> s_loads
    const int ry = rois[r * 4 + 1];
    const int rw = rois[r * 4 + 2];
    const int rh = rois[r * 4 + 3];

    // Match JAX: f32 rn divide; floor(coord + i*rl) with separate rn mul+add.
    const float rlx = (float)rw / 7.0f;
    const float rly = (float)rh / 7.0f;
    const int kw = __builtin_amdgcn_readfirstlane((int)rlx);  // floor(rl), 1..8
    const int kh = __builtin_amdgcn_readfirstlane((int)rly);

    // Band starts: lane plays py for lanes 0..6; hoist ALL readlanes out of
    // any divergent region into named scalars.
    const int syv = (int)floorf(__fadd_rn((float)ry, __fmul_rn((float)lane, rly)));
    const int sy0 = __builtin_amdgcn_readlane(syv, 0);
    const int sy1 = __builtin_amdgcn_readlane(syv, 1);
    const int sy2 = __builtin_amdgcn_readlane(syv, 2);
    const int sy3 = __builtin_amdgcn_readlane(syv, 3);
    const int sy4 = __builtin_amdgcn_readlane(syv, 4);
    const int sy5 = __builtin_amdgcn_readlane(syv, 5);
    const int sy6 = __builtin_amdgcn_readlane(syv, 6);

    const float* xc0 = x + ((size_t)cp << 13);   // two channels, 8192 floats
    const float NEG = -3.402823466e38f;
    // Only columns [rx, rx+rw) are ever consumed by phase 2.
    const bool act = (unsigned)(lane - rx) < (unsigned)rw;

    // ---- Phase 1: vertical band maxes for 2 channels; lane = abs column. ----
#define BAND(PY, SY, KH)                                                      \
    {                                                                         \
        const float* p = xc0 + (SY) * HW + lane;                              \
        float v0[KH], v1[KH];                                                 \
        _Pragma("unroll")                                                     \
        for (int j = 0; j < KH; ++j) { v0[j] = p[j * HW];                     \
                                       v1[j] = p[j * HW + 4096]; }            \
        float m0 = NEG, m1 = NEG;                                             \
        _Pragma("unroll")                                                     \
        for (int j = 0; j < KH; ++j) {                                        \
            m0 = fmaxf(m0, (j < kh) ? v0[j] : NEG);                           \
            m1 = fmaxf(m1, (j < kh) ? v1[j] : NEG);                           \
        }                                                                     \
        slab[(PY) * SW + lane] = m0;                                          \
        slab[(P + (PY)) * SW + lane] = m1;                                    \
    }

    if (kh <= 4) {         // uniform branch outermost
        if (act) {         // single divergence point; body = loads/fmax/ds only
            BAND(0,sy0,4) BAND(1,sy1,4) BAND(2,sy2,4) BAND(3,sy3,4)
            BAND(4,sy4,4) BAND(5,sy5,4) BAND(6,sy6,4)
        }
    } else {
        if (act) {
            BAND(0,sy0,8) BAND(1,sy1,8) BAND(2,sy2,8) BAND(3,sy3,8)
            BAND(4,sy4,8) BAND(5,sy5,8) BAND(6,sy6,8)
        }
    }
#undef BAND

    // ---- Phase 2: one lane per bin; unconditional ds_reads, cndmask keep. ----
    // Kept slots [sx, sx+kw) always lie in the written range [rx, rx+rw):
    // floor(x+6w/7)+floor(w/7) <= x+w, with equality only when 7|w, in which
    // case the last kept index is x+w-1.
    if (lane < P * P) {
        const int py = lane / 7;
        const int px = lane - py * 7;
        const int sx = (int)floorf(__fadd_rn((float)rx, __fmul_rn((float)px, rlx)));
        const float* w0 = slab + py * SW + sx;
        const float* w1 = w0 + P * SW;
        float m0, m1;
        if (kw <= 4) {
            float a0 = w0[0], a1 = w0[1], a2 = w0[2], a3 = w0[3];
            float b0 = w1[0], b1 = w1[1], b2 = w1[2], b3 = w1[3];
            m0 = a0; m1 = b0;
            m0 = fmaxf(m0, (1 < kw) ? a1 : NEG); m1 = fmaxf(m1, (1 < kw) ? b1 : NEG);
            m0 = fmaxf(m0, (2 < kw) ? a2 : NEG); m1 = fmaxf(m1, (2 < kw) ? b2 : NEG);
            m0 = fmaxf(m0, (3 < kw) ? a3 : NEG); m1 = fmaxf(m1, (3 < kw) ? b3 : NEG);
        } else {
            float a0 = w0[0], a1 = w0[1], a2 = w0[2], a3 = w0[3];
            float a4 = w0[4], a5 = w0[5], a6 = w0[6], a7 = w0[7];
            float b0 = w1[0], b1 = w1[1], b2 = w1[2], b3 = w1[3];
            float b4 = w1[4], b5 = w1[5], b6 = w1[6], b7 = w1[7];
            m0 = fmaxf(fmaxf(fmaxf(a0, a1), fmaxf(a2, a3)), a4);  // kw >= 5
            m1 = fmaxf(fmaxf(fmaxf(b0, b1), fmaxf(b2, b3)), b4);
            m0 = fmaxf(m0, (5 < kw) ? a5 : NEG); m1 = fmaxf(m1, (5 < kw) ? b5 : NEG);
            m0 = fmaxf(m0, (6 < kw) ? a6 : NEG); m1 = fmaxf(m1, (6 < kw) ? b6 : NEG);
            m0 = fmaxf(m0, (7 < kw) ? a7 : NEG); m1 = fmaxf(m1, (7 < kw) ? b7 : NEG);
        }
        const size_t base = ((size_t)(r << 8) + (cp << 1)) * (P * P) + lane;
        out[base] = m0;                       // 196B contiguous per wave
        out[base + P * P] = m1;               // adjacent 196B block
    }
}

extern "C" void kernel_launch(void* const* d_in, const int* in_sizes, int n_in,
                              void* d_out, int out_size, void* d_ws, size_t ws_size,
                              hipStream_t stream) {
    const float* x = (const float*)d_in[0];
    const int* rois = (const int*)d_in[1];
    float* out = (float*)d_out;

    const int grid = (R * C / 2) / 4;  // 16384 waves (r x 128 ch-pairs), 4/block
    roi_pool_kernel<<<grid, 256, 0, stream>>>(x, rois, out);
}